// Round 2
// baseline (694.983 us; speedup 1.0000x reference)
//
#include <hip/hip_runtime.h>
#include <hip/hip_bf16.h>
#include <stdint.h>

using u16 = unsigned short;
using u32 = unsigned int;

// ---------- bf16 helpers ----------
__device__ __forceinline__ float bf2f(u16 u) {
    union { u32 i; float f; } c; c.i = ((u32)u) << 16; return c.f;
}
__device__ __forceinline__ u16 f2bf(float f) {
    union { float f; u32 i; } c; c.f = f;
    u32 u = c.i;
    u32 r = (u + 0x7fffu + ((u >> 16) & 1u)) >> 16;  // RNE
    return (u16)r;
}

// ---------- zero-fill (capture-safe memset replacement) ----------
__global__ __launch_bounds__(256) void zero_k(int* __restrict__ p, int n) {
    int i = blockIdx.x * 256 + threadIdx.x;
    if (i < n) p[i] = 0;
}

// ---------- cast fp32 -> bf16 (vectorized) ----------
__global__ __launch_bounds__(256) void cast_bf16_k(const float* __restrict__ x,
                                                   u16* __restrict__ y, int n4) {
    int i = blockIdx.x * 256 + threadIdx.x;
    if (i < n4) {
        float4 v = reinterpret_cast<const float4*>(x)[i];
        ushort4 o;
        o.x = f2bf(v.x); o.y = f2bf(v.y); o.z = f2bf(v.z); o.w = f2bf(v.w);
        reinterpret_cast<ushort4*>(y)[i] = o;
    }
}

// ---------- build transposed concat weight: Wt[n][k] = (k<K1 ? Wl[k][n] : Wr[k-K1][n]) ----------
__global__ __launch_bounds__(256) void prep_w_k(const float* __restrict__ Wl,
                                                const float* __restrict__ Wr,
                                                u16* __restrict__ Wt, int K1, int KT) {
    int idx = blockIdx.x * 256 + threadIdx.x;
    if (idx < 256 * KT) {
        int n = idx / KT, k = idx - n * KT;
        float v = (k < K1) ? Wl[k * 256 + n] : Wr[(k - K1) * 256 + n];
        Wt[idx] = f2bf(v);
    }
}

// ---------- degree count ----------
__global__ __launch_bounds__(256) void count_deg_k(const int* __restrict__ dui,
                                                   const int* __restrict__ diu,
                                                   int* __restrict__ ci, int* __restrict__ cu, int E) {
    int e = blockIdx.x * 256 + threadIdx.x;
    if (e < E) {
        atomicAdd(&ci[dui[e]], 1);
        atomicAdd(&cu[diu[e]], 1);
    }
}

// ---------- exclusive scan (3-kernel), 2048 elems / block ----------
__global__ __launch_bounds__(256) void scan_blk_k(const int* __restrict__ cnt,
                                                  int* __restrict__ off,
                                                  int* __restrict__ partial, int n) {
    __shared__ int wsum[4];
    int t = threadIdx.x, b = blockIdx.x;
    int base = b * 2048 + t * 8;
    int v[8];
#pragma unroll
    for (int i = 0; i < 8; i++) v[i] = (base + i < n) ? cnt[base + i] : 0;
    int tsum = 0;
#pragma unroll
    for (int i = 0; i < 8; i++) tsum += v[i];
    int lane = t & 63;
    int incl = tsum;
#pragma unroll
    for (int d = 1; d < 64; d <<= 1) {
        int o = __shfl_up(incl, d, 64);
        if (lane >= d) incl += o;
    }
    if (lane == 63) wsum[t >> 6] = incl;
    __syncthreads();
    int woff = 0;
    for (int w = 0; w < (t >> 6); ++w) woff += wsum[w];
    int run = woff + incl - tsum;
#pragma unroll
    for (int i = 0; i < 8; i++) {
        if (base + i < n) off[base + i] = run;
        run += v[i];
    }
    if (t == 0) partial[b] = wsum[0] + wsum[1] + wsum[2] + wsum[3];
}

__global__ void scan_part_k(int* __restrict__ p, int nb) {  // 1 wave, nb<=64
    int l = threadIdx.x;
    int v = (l < nb) ? p[l] : 0;
    int incl = v;
#pragma unroll
    for (int d = 1; d < 64; d <<= 1) {
        int o = __shfl_up(incl, d, 64);
        if (l >= d) incl += o;
    }
    if (l < nb) p[l] = incl - v;
}

__global__ __launch_bounds__(256) void scan_add_k(int* __restrict__ off, int* __restrict__ cursor,
                                                  const int* __restrict__ part, int n) {
    int i = blockIdx.x * 256 + threadIdx.x;
    if (i < n) {
        int v = off[i] + part[i >> 11];
        off[i] = v;
        cursor[i] = v;
    }
}

// ---------- CSR bucket fill: csr[p] = src id, grouped by dst ----------
__global__ __launch_bounds__(256) void fill_csr_k(const int* __restrict__ src,
                                                  const int* __restrict__ dst,
                                                  int* __restrict__ cursor, int* __restrict__ csr, int E) {
    int e = blockIdx.x * 256 + threadIdx.x;
    if (e < E) {
        int p = atomicAdd(&cursor[dst[e]], 1);
        csr[p] = src[e];
    }
}

// ---------- segment-mean aggregation: one wave per dst node ----------
template <int D>
__global__ __launch_bounds__(256) void agg_mean_k(const u16* __restrict__ feat,
                                                  const int* __restrict__ csr,
                                                  const int* __restrict__ off,
                                                  const int* __restrict__ cnt,
                                                  u16* __restrict__ out, int n) {
    int gw = (blockIdx.x * 256 + threadIdx.x) >> 6;
    if (gw >= n) return;
    int lane = threadIdx.x & 63;
    int beg = off[gw];
    int c = cnt[gw];
    constexpr int V = D / 64;  // bf16 elems per lane: 2 or 4
    float acc[V];
#pragma unroll
    for (int i = 0; i < V; i++) acc[i] = 0.f;
    const u16* fl = feat + lane * V;
    int j = 0;
    for (; j + 2 <= c; j += 2) {
        int s0 = csr[beg + j], s1 = csr[beg + j + 1];
        if constexpr (V == 2) {
            u32 a = *(const u32*)(fl + (size_t)s0 * D);
            u32 b = *(const u32*)(fl + (size_t)s1 * D);
            acc[0] += bf2f((u16)a) + bf2f((u16)b);
            acc[1] += bf2f((u16)(a >> 16)) + bf2f((u16)(b >> 16));
        } else {
            uint2 a = *(const uint2*)(fl + (size_t)s0 * D);
            uint2 b = *(const uint2*)(fl + (size_t)s1 * D);
            acc[0] += bf2f((u16)a.x) + bf2f((u16)b.x);
            acc[1] += bf2f((u16)(a.x >> 16)) + bf2f((u16)(b.x >> 16));
            acc[2] += bf2f((u16)a.y) + bf2f((u16)b.y);
            acc[3] += bf2f((u16)(a.y >> 16)) + bf2f((u16)(b.y >> 16));
        }
    }
    if (j < c) {
        int s0 = csr[beg + j];
        if constexpr (V == 2) {
            u32 a = *(const u32*)(fl + (size_t)s0 * D);
            acc[0] += bf2f((u16)a);
            acc[1] += bf2f((u16)(a >> 16));
        } else {
            uint2 a = *(const uint2*)(fl + (size_t)s0 * D);
            acc[0] += bf2f((u16)a.x);
            acc[1] += bf2f((u16)(a.x >> 16));
            acc[2] += bf2f((u16)a.y);
            acc[3] += bf2f((u16)(a.y >> 16));
        }
    }
    float inv = 1.0f / (float)((c > 0) ? c : 1);
    if constexpr (V == 2) {
        u32 o = (u32)f2bf(acc[0] * inv) | ((u32)f2bf(acc[1] * inv) << 16);
        *(u32*)(out + (size_t)gw * D + lane * 2) = o;
    } else {
        uint2 o;
        o.x = (u32)f2bf(acc[0] * inv) | ((u32)f2bf(acc[1] * inv) << 16);
        o.y = (u32)f2bf(acc[2] * inv) | ((u32)f2bf(acc[3] * inv) << 16);
        *(uint2*)(out + (size_t)gw * D + lane * 4) = o;
    }
}

// ---------- concat-K GEMM: C = [A1|A2] @ Bt^T + bias, optional relu ----------
// A1,A2: M_pad x (KTOT/2) bf16 row-major. Bt: 256 x KTOT bf16 (row n, col k).
// Tile 128x128, BK=32, 4 waves (2x2), each wave 64x64 via 4x4 16x16x32 MFMA frags.
typedef __attribute__((ext_vector_type(8))) short bf16x8;
typedef __attribute__((ext_vector_type(4))) float f32x4;

template <int KTOT, bool RELU, bool OUTBF16>
__global__ __launch_bounds__(256) void gemm_cat_k(const u16* __restrict__ A1,
                                                  const u16* __restrict__ A2,
                                                  const u16* __restrict__ Bt,
                                                  const float* __restrict__ bias,
                                                  void* __restrict__ Cout, int M_real) {
    constexpr int KH = KTOT / 2;
    __shared__ u16 As[128 * 32];
    __shared__ u16 Bs[128 * 32];
    int bid = blockIdx.x;
    int bm = bid >> 1, bn = bid & 1;
    int t = threadIdx.x;
    int lane = t & 63;
    int w = t >> 6, wm = w >> 1, wn = w & 1;
    int r16 = lane & 15, kg = lane >> 4;

    f32x4 acc[4][4];
#pragma unroll
    for (int i = 0; i < 4; i++)
#pragma unroll
        for (int j = 0; j < 4; j++) acc[i][j] = (f32x4){0.f, 0.f, 0.f, 0.f};

    for (int k0 = 0; k0 < KTOT; k0 += 32) {
        if (k0) __syncthreads();
        const u16* Ab;
        int ka;
        if (k0 < KH) { Ab = A1; ka = k0; } else { Ab = A2; ka = k0 - KH; }
#pragma unroll
        for (int p = 0; p < 2; p++) {
            int flat = p * 256 + t;
            int row = flat >> 2, cch = flat & 3;
            const u16* asrc = Ab + (size_t)(bm * 128 + row) * KH + ka + cch * 8;
            __builtin_amdgcn_global_load_lds(
                (const __attribute__((address_space(1))) u32*)asrc,
                (__attribute__((address_space(3))) u32*)(As + flat * 8), 16, 0, 0);
            const u16* bsrc = Bt + (size_t)(bn * 128 + row) * KTOT + k0 + cch * 8;
            __builtin_amdgcn_global_load_lds(
                (const __attribute__((address_space(1))) u32*)bsrc,
                (__attribute__((address_space(3))) u32*)(Bs + flat * 8), 16, 0, 0);
        }
        __syncthreads();
        bf16x8 af[4], bfr[4];
#pragma unroll
        for (int mi = 0; mi < 4; mi++)
            af[mi] = *(const bf16x8*)(As + (wm * 64 + mi * 16 + r16) * 32 + kg * 8);
#pragma unroll
        for (int ni = 0; ni < 4; ni++)
            bfr[ni] = *(const bf16x8*)(Bs + (wn * 64 + ni * 16 + r16) * 32 + kg * 8);
#pragma unroll
        for (int mi = 0; mi < 4; mi++)
#pragma unroll
            for (int ni = 0; ni < 4; ni++)
                acc[mi][ni] = __builtin_amdgcn_mfma_f32_16x16x32_bf16(af[mi], bfr[ni], acc[mi][ni], 0, 0, 0);
    }

    // epilogue: D layout col=lane&15, row=(lane>>4)*4+r
    int rbase = bm * 128 + wm * 64 + (lane >> 4) * 4;
    int cb = bn * 128 + wn * 64 + (lane & 15);
    float bv[4];
#pragma unroll
    for (int ni = 0; ni < 4; ni++) bv[ni] = bias[cb + ni * 16];
#pragma unroll
    for (int mi = 0; mi < 4; mi++) {
#pragma unroll
        for (int r = 0; r < 4; r++) {
            int rowg = rbase + mi * 16 + r;
            if (rowg < M_real) {
#pragma unroll
                for (int ni = 0; ni < 4; ni++) {
                    int colg = cb + ni * 16;
                    float v = acc[mi][ni][r] + bv[ni];
                    if (RELU) v = fmaxf(v, 0.f);
                    if (OUTBF16)
                        ((u16*)Cout)[(size_t)rowg * 256 + colg] = f2bf(v);
                    else
                        ((float*)Cout)[(size_t)rowg * 256 + colg] = v;
                }
            }
        }
    }
}

// ---------- launch ----------
extern "C" void kernel_launch(void* const* d_in, const int* in_sizes, int n_in,
                              void* d_out, int out_size, void* d_ws, size_t ws_size,
                              hipStream_t stream) {
    const float* x_user = (const float*)d_in[0];
    const float* x_item = (const float*)d_in[1];
    const float* W1l_ui = (const float*)d_in[2];
    const float* W1r_ui = (const float*)d_in[3];
    const float* b1_ui  = (const float*)d_in[4];
    const float* W1l_iu = (const float*)d_in[5];
    const float* W1r_iu = (const float*)d_in[6];
    const float* b1_iu  = (const float*)d_in[7];
    const float* W2l_ui = (const float*)d_in[8];
    const float* W2r_ui = (const float*)d_in[9];
    const float* b2_ui  = (const float*)d_in[10];
    const float* W2l_iu = (const float*)d_in[11];
    const float* W2r_iu = (const float*)d_in[12];
    const float* b2_iu  = (const float*)d_in[13];
    const int* src_ui = (const int*)d_in[14];
    const int* dst_ui = (const int*)d_in[15];
    const int* src_iu = (const int*)d_in[16];
    const int* dst_iu = (const int*)d_in[17];
    const int E = in_sizes[14];

    const int MU = 100000, MI = 50000;
    const int MUP = 100096, MIP = 50048;  // padded to 128-row multiples

    char* ws = (char*)d_ws;
    // Region AB (phase1: xu_bf, xi_bf, agg1_user, agg1_item | phase2: agg2_user, agg2_item)
    u16* xu_bf     = (u16*)(ws + 0);                    // 25,624,576 B
    u16* xi_bf     = (u16*)(ws + 25624576);             // 12,812,288 B
    u16* agg1_user = (u16*)(ws + 38436864);             // 25,624,576 B
    u16* agg1_item = (u16*)(ws + 64061440);             // 12,812,288 B
    u16* agg2_user = (u16*)(ws + 0);                    // 51,249,152 B (aliases phase1)
    u16* agg2_item = (u16*)(ws + 51249152);             // 25,624,576 B (aliases phase1)
    // Region C: h
    size_t C0 = 76873728;
    u16* h_user = (u16*)(ws + C0);                      // 51,249,152 B
    u16* h_item = (u16*)(ws + C0 + 51249152);           // 25,624,576 B
    // Weights (transposed concat, bf16)
    size_t W0 = C0 + 76873728;  // 153,747,456
    u16* Wt1_ui = (u16*)(ws + W0);
    u16* Wt1_iu = (u16*)(ws + W0 + 131072);
    u16* Wt2_ui = (u16*)(ws + W0 + 262144);
    u16* Wt2_iu = (u16*)(ws + W0 + 524288);
    // Index scratch
    size_t I0 = W0 + 786432;  // 154,533,888
    int* cnt_item = (int*)(ws + I0);
    int* cnt_user = (int*)(ws + I0 + 200000);
    int* off_item = (int*)(ws + I0 + 600000);
    int* off_user = (int*)(ws + I0 + 800000);
    int* cur_item = (int*)(ws + I0 + 1200000);
    int* cur_user = (int*)(ws + I0 + 1400000);
    int* part_a   = (int*)(ws + I0 + 1800000);
    int* part_b   = (int*)(ws + I0 + 1800256);
    int* csr_ui   = (int*)(ws + I0 + 1800512);
    int* csr_iu   = (int*)(ws + I0 + 1800512 + 2400000);

    // zero degree counters (cnt_item | cnt_user are adjacent: 150000 ints)
    zero_k<<<dim3((150000 + 255) / 256), dim3(256), 0, stream>>>(cnt_item, 150000);

    // casts + weight prep
    cast_bf16_k<<<dim3((MU * 128 / 4 + 255) / 256), dim3(256), 0, stream>>>(x_user, xu_bf, MU * 128 / 4);
    cast_bf16_k<<<dim3((MI * 128 / 4 + 255) / 256), dim3(256), 0, stream>>>(x_item, xi_bf, MI * 128 / 4);
    prep_w_k<<<dim3(256), dim3(256), 0, stream>>>(W1l_ui, W1r_ui, Wt1_ui, 128, 256);
    prep_w_k<<<dim3(256), dim3(256), 0, stream>>>(W1l_iu, W1r_iu, Wt1_iu, 128, 256);
    prep_w_k<<<dim3(512), dim3(256), 0, stream>>>(W2l_ui, W2r_ui, Wt2_ui, 256, 512);
    prep_w_k<<<dim3(512), dim3(256), 0, stream>>>(W2l_iu, W2r_iu, Wt2_iu, 256, 512);

    // degree + CSR build
    int gE = (E + 255) / 256;
    count_deg_k<<<dim3(gE), dim3(256), 0, stream>>>(dst_ui, dst_iu, cnt_item, cnt_user, E);
    scan_blk_k<<<dim3(25), dim3(256), 0, stream>>>(cnt_item, off_item, part_a, MI);
    scan_part_k<<<dim3(1), dim3(64), 0, stream>>>(part_a, 25);
    scan_add_k<<<dim3((MI + 255) / 256), dim3(256), 0, stream>>>(off_item, cur_item, part_a, MI);
    scan_blk_k<<<dim3(49), dim3(256), 0, stream>>>(cnt_user, off_user, part_b, MU);
    scan_part_k<<<dim3(1), dim3(64), 0, stream>>>(part_b, 49);
    scan_add_k<<<dim3((MU + 255) / 256), dim3(256), 0, stream>>>(off_user, cur_user, part_b, MU);
    fill_csr_k<<<dim3(gE), dim3(256), 0, stream>>>(src_ui, dst_ui, cur_item, csr_ui, E);
    fill_csr_k<<<dim3(gE), dim3(256), 0, stream>>>(src_iu, dst_iu, cur_user, csr_iu, E);

    // layer 1: aggregate (D=128) then fused concat-GEMM + relu -> h (bf16)
    agg_mean_k<128><<<dim3((MI + 3) / 4), dim3(256), 0, stream>>>(xu_bf, csr_ui, off_item, cnt_item, agg1_item, MI);
    agg_mean_k<128><<<dim3((MU + 3) / 4), dim3(256), 0, stream>>>(xi_bf, csr_iu, off_user, cnt_user, agg1_user, MU);
    gemm_cat_k<256, true, true><<<dim3((MIP / 128) * 2), dim3(256), 0, stream>>>(agg1_item, xi_bf, Wt1_ui, b1_ui, h_item, MI);
    gemm_cat_k<256, true, true><<<dim3((MUP / 128) * 2), dim3(256), 0, stream>>>(agg1_user, xu_bf, Wt1_iu, b1_iu, h_user, MU);

    // layer 2: aggregate (D=256) then concat-GEMM -> d_out (fp32)
    agg_mean_k<256><<<dim3((MI + 3) / 4), dim3(256), 0, stream>>>(h_user, csr_ui, off_item, cnt_item, agg2_item, MI);
    agg_mean_k<256><<<dim3((MU + 3) / 4), dim3(256), 0, stream>>>(h_item, csr_iu, off_user, cnt_user, agg2_user, MU);
    float* out = (float*)d_out;
    gemm_cat_k<512, false, false><<<dim3((MUP / 128) * 2), dim3(256), 0, stream>>>(agg2_user, h_user, Wt2_iu, b2_iu, out, MU);
    gemm_cat_k<512, false, false><<<dim3((MIP / 128) * 2), dim3(256), 0, stream>>>(agg2_item, h_item, Wt2_ui, b2_iu, out + (size_t)MU * 256, MI);
}

// Round 3
// 665.213 us; speedup vs baseline: 1.0448x; 1.0448x over previous
//
#include <hip/hip_runtime.h>
#include <hip/hip_bf16.h>
#include <stdint.h>

using u16 = unsigned short;
using u32 = unsigned int;

// ---------- bf16 helpers ----------
__device__ __forceinline__ float bf2f(u16 u) {
    union { u32 i; float f; } c; c.i = ((u32)u) << 16; return c.f;
}
__device__ __forceinline__ u16 f2bf(float f) {
    union { float f; u32 i; } c; c.f = f;
    u32 u = c.i;
    u32 r = (u + 0x7fffu + ((u >> 16) & 1u)) >> 16;  // RNE
    return (u16)r;
}

// ---------- zero-fill (capture-safe memset replacement) ----------
__global__ __launch_bounds__(256) void zero_k(int* __restrict__ p, int n) {
    int i = blockIdx.x * 256 + threadIdx.x;
    if (i < n) p[i] = 0;
}

// ---------- cast fp32 -> bf16 (vectorized) ----------
__global__ __launch_bounds__(256) void cast_bf16_k(const float* __restrict__ x,
                                                   u16* __restrict__ y, int n4) {
    int i = blockIdx.x * 256 + threadIdx.x;
    if (i < n4) {
        float4 v = reinterpret_cast<const float4*>(x)[i];
        ushort4 o;
        o.x = f2bf(v.x); o.y = f2bf(v.y); o.z = f2bf(v.z); o.w = f2bf(v.w);
        reinterpret_cast<ushort4*>(y)[i] = o;
    }
}

// ---------- build transposed concat weight: Wt[n][k] = (k<K1 ? Wl[k][n] : Wr[k-K1][n]) ----------
__global__ __launch_bounds__(256) void prep_w_k(const float* __restrict__ Wl,
                                                const float* __restrict__ Wr,
                                                u16* __restrict__ Wt, int K1, int KT) {
    int idx = blockIdx.x * 256 + threadIdx.x;
    if (idx < 256 * KT) {
        int n = idx / KT, k = idx - n * KT;
        float v = (k < K1) ? Wl[k * 256 + n] : Wr[(k - K1) * 256 + n];
        Wt[idx] = f2bf(v);
    }
}

// ---------- degree count ----------
__global__ __launch_bounds__(256) void count_deg_k(const int* __restrict__ dui,
                                                   const int* __restrict__ diu,
                                                   int* __restrict__ ci, int* __restrict__ cu, int E) {
    int e = blockIdx.x * 256 + threadIdx.x;
    if (e < E) {
        atomicAdd(&ci[dui[e]], 1);
        atomicAdd(&cu[diu[e]], 1);
    }
}

// ---------- exclusive scan (3-kernel), 2048 elems / block ----------
__global__ __launch_bounds__(256) void scan_blk_k(const int* __restrict__ cnt,
                                                  int* __restrict__ off,
                                                  int* __restrict__ partial, int n) {
    __shared__ int wsum[4];
    int t = threadIdx.x, b = blockIdx.x;
    int base = b * 2048 + t * 8;
    int v[8];
#pragma unroll
    for (int i = 0; i < 8; i++) v[i] = (base + i < n) ? cnt[base + i] : 0;
    int tsum = 0;
#pragma unroll
    for (int i = 0; i < 8; i++) tsum += v[i];
    int lane = t & 63;
    int incl = tsum;
#pragma unroll
    for (int d = 1; d < 64; d <<= 1) {
        int o = __shfl_up(incl, d, 64);
        if (lane >= d) incl += o;
    }
    if (lane == 63) wsum[t >> 6] = incl;
    __syncthreads();
    int woff = 0;
    for (int w = 0; w < (t >> 6); ++w) woff += wsum[w];
    int run = woff + incl - tsum;
#pragma unroll
    for (int i = 0; i < 8; i++) {
        if (base + i < n) off[base + i] = run;
        run += v[i];
    }
    if (t == 0) partial[b] = wsum[0] + wsum[1] + wsum[2] + wsum[3];
}

__global__ void scan_part_k(int* __restrict__ p, int nb) {  // 1 wave, nb<=64
    int l = threadIdx.x;
    int v = (l < nb) ? p[l] : 0;
    int incl = v;
#pragma unroll
    for (int d = 1; d < 64; d <<= 1) {
        int o = __shfl_up(incl, d, 64);
        if (l >= d) incl += o;
    }
    if (l < nb) p[l] = incl - v;
}

__global__ __launch_bounds__(256) void scan_add_k(int* __restrict__ off, int* __restrict__ cursor,
                                                  const int* __restrict__ part, int n) {
    int i = blockIdx.x * 256 + threadIdx.x;
    if (i < n) {
        int v = off[i] + part[i >> 11];
        off[i] = v;
        cursor[i] = v;
    }
}

// ---------- CSR bucket fill: csr[p] = src id, grouped by dst ----------
__global__ __launch_bounds__(256) void fill_csr_k(const int* __restrict__ src,
                                                  const int* __restrict__ dst,
                                                  int* __restrict__ cursor, int* __restrict__ csr, int E) {
    int e = blockIdx.x * 256 + threadIdx.x;
    if (e < E) {
        int p = atomicAdd(&cursor[dst[e]], 1);
        csr[p] = src[e];
    }
}

// ---------- segment-mean aggregation: one wave per dst node, 16B/lane wide loads ----------
// D=128: 16 lanes cover a 256B row -> 4 edges per wave-iteration.
// D=256: 32 lanes cover a 512B row -> 2 edges per wave-iteration.
// Cross-group partials combined via shfl_xor; lanes of group 0 write the row.
__device__ __forceinline__ void acc8(float* acc, uint4 a) {
    acc[0] += bf2f((u16)a.x); acc[1] += bf2f((u16)(a.x >> 16));
    acc[2] += bf2f((u16)a.y); acc[3] += bf2f((u16)(a.y >> 16));
    acc[4] += bf2f((u16)a.z); acc[5] += bf2f((u16)(a.z >> 16));
    acc[6] += bf2f((u16)a.w); acc[7] += bf2f((u16)(a.w >> 16));
}

template <int D>
__global__ __launch_bounds__(256) void agg_mean_k(const u16* __restrict__ feat,
                                                  const int* __restrict__ csr,
                                                  const int* __restrict__ off,
                                                  const int* __restrict__ cnt,
                                                  u16* __restrict__ out, int n) {
    int gw = (blockIdx.x * 256 + threadIdx.x) >> 6;
    if (gw >= n) return;
    int lane = threadIdx.x & 63;
    constexpr int LPR = D / 8;        // lanes per row (8 bf16 = 16B per lane)
    constexpr int GRP = 64 / LPR;     // edges processed per wave-iteration
    int g = lane / LPR;               // edge-group id
    int sl = lane % LPR;              // 16B slot within row
    int beg = off[gw], c = cnt[gw];
    float acc[8];
#pragma unroll
    for (int i = 0; i < 8; i++) acc[i] = 0.f;
    const u16* fp = feat + sl * 8;
    int j = g;
    for (; j + GRP < c; j += 2 * GRP) {  // two gathers in flight
        int s0 = csr[beg + j], s1 = csr[beg + j + GRP];
        uint4 a = *(const uint4*)(fp + (size_t)s0 * D);
        uint4 b = *(const uint4*)(fp + (size_t)s1 * D);
        acc8(acc, a);
        acc8(acc, b);
    }
    if (j < c) {
        uint4 a = *(const uint4*)(fp + (size_t)csr[beg + j] * D);
        acc8(acc, a);
    }
#pragma unroll
    for (int i = 0; i < 8; i++) {
        if constexpr (GRP == 4) acc[i] += __shfl_xor(acc[i], 16, 64);
        acc[i] += __shfl_xor(acc[i], 32, 64);
    }
    if (g == 0) {
        float inv = 1.0f / (float)((c > 0) ? c : 1);
        uint4 o;
        o.x = (u32)f2bf(acc[0] * inv) | ((u32)f2bf(acc[1] * inv) << 16);
        o.y = (u32)f2bf(acc[2] * inv) | ((u32)f2bf(acc[3] * inv) << 16);
        o.z = (u32)f2bf(acc[4] * inv) | ((u32)f2bf(acc[5] * inv) << 16);
        o.w = (u32)f2bf(acc[6] * inv) | ((u32)f2bf(acc[7] * inv) << 16);
        *(uint4*)(out + (size_t)gw * D + sl * 8) = o;
    }
}

// ---------- concat-K GEMM: C = [A1|A2] @ Bt^T + bias, optional relu ----------
// A1,A2: M_pad x (KTOT/2) bf16 row-major. Bt: 256 x KTOT bf16 (row n, col k).
// Tile 128x128, BK=32, 4 waves (2x2), each wave 64x64 via 4x4 16x16x32 MFMA frags.
typedef __attribute__((ext_vector_type(8))) short bf16x8;
typedef __attribute__((ext_vector_type(4))) float f32x4;

template <int KTOT, bool RELU, bool OUTBF16>
__global__ __launch_bounds__(256) void gemm_cat_k(const u16* __restrict__ A1,
                                                  const u16* __restrict__ A2,
                                                  const u16* __restrict__ Bt,
                                                  const float* __restrict__ bias,
                                                  void* __restrict__ Cout, int M_real) {
    constexpr int KH = KTOT / 2;
    __shared__ u16 As[128 * 32];
    __shared__ u16 Bs[128 * 32];
    int bid = blockIdx.x;
    int bm = bid >> 1, bn = bid & 1;
    int t = threadIdx.x;
    int lane = t & 63;
    int w = t >> 6, wm = w >> 1, wn = w & 1;
    int r16 = lane & 15, kg = lane >> 4;

    f32x4 acc[4][4];
#pragma unroll
    for (int i = 0; i < 4; i++)
#pragma unroll
        for (int j = 0; j < 4; j++) acc[i][j] = (f32x4){0.f, 0.f, 0.f, 0.f};

    for (int k0 = 0; k0 < KTOT; k0 += 32) {
        if (k0) __syncthreads();
        const u16* Ab;
        int ka;
        if (k0 < KH) { Ab = A1; ka = k0; } else { Ab = A2; ka = k0 - KH; }
#pragma unroll
        for (int p = 0; p < 2; p++) {
            int flat = p * 256 + t;
            int row = flat >> 2, cch = flat & 3;
            const u16* asrc = Ab + (size_t)(bm * 128 + row) * KH + ka + cch * 8;
            __builtin_amdgcn_global_load_lds(
                (const __attribute__((address_space(1))) u32*)asrc,
                (__attribute__((address_space(3))) u32*)(As + flat * 8), 16, 0, 0);
            const u16* bsrc = Bt + (size_t)(bn * 128 + row) * KTOT + k0 + cch * 8;
            __builtin_amdgcn_global_load_lds(
                (const __attribute__((address_space(1))) u32*)bsrc,
                (__attribute__((address_space(3))) u32*)(Bs + flat * 8), 16, 0, 0);
        }
        __syncthreads();
        bf16x8 af[4], bfr[4];
#pragma unroll
        for (int mi = 0; mi < 4; mi++)
            af[mi] = *(const bf16x8*)(As + (wm * 64 + mi * 16 + r16) * 32 + kg * 8);
#pragma unroll
        for (int ni = 0; ni < 4; ni++)
            bfr[ni] = *(const bf16x8*)(Bs + (wn * 64 + ni * 16 + r16) * 32 + kg * 8);
#pragma unroll
        for (int mi = 0; mi < 4; mi++)
#pragma unroll
            for (int ni = 0; ni < 4; ni++)
                acc[mi][ni] = __builtin_amdgcn_mfma_f32_16x16x32_bf16(af[mi], bfr[ni], acc[mi][ni], 0, 0, 0);
    }

    // epilogue: D layout col=lane&15, row=(lane>>4)*4+r
    int rbase = bm * 128 + wm * 64 + (lane >> 4) * 4;
    int cb = bn * 128 + wn * 64 + (lane & 15);
    float bv[4];
#pragma unroll
    for (int ni = 0; ni < 4; ni++) bv[ni] = bias[cb + ni * 16];
#pragma unroll
    for (int mi = 0; mi < 4; mi++) {
#pragma unroll
        for (int r = 0; r < 4; r++) {
            int rowg = rbase + mi * 16 + r;
            if (rowg < M_real) {
#pragma unroll
                for (int ni = 0; ni < 4; ni++) {
                    int colg = cb + ni * 16;
                    float v = acc[mi][ni][r] + bv[ni];
                    if (RELU) v = fmaxf(v, 0.f);
                    if (OUTBF16)
                        ((u16*)Cout)[(size_t)rowg * 256 + colg] = f2bf(v);
                    else
                        ((float*)Cout)[(size_t)rowg * 256 + colg] = v;
                }
            }
        }
    }
}

// ---------- launch ----------
extern "C" void kernel_launch(void* const* d_in, const int* in_sizes, int n_in,
                              void* d_out, int out_size, void* d_ws, size_t ws_size,
                              hipStream_t stream) {
    const float* x_user = (const float*)d_in[0];
    const float* x_item = (const float*)d_in[1];
    const float* W1l_ui = (const float*)d_in[2];
    const float* W1r_ui = (const float*)d_in[3];
    const float* b1_ui  = (const float*)d_in[4];
    const float* W1l_iu = (const float*)d_in[5];
    const float* W1r_iu = (const float*)d_in[6];
    const float* b1_iu  = (const float*)d_in[7];
    const float* W2l_ui = (const float*)d_in[8];
    const float* W2r_ui = (const float*)d_in[9];
    const float* b2_ui  = (const float*)d_in[10];
    const float* W2l_iu = (const float*)d_in[11];
    const float* W2r_iu = (const float*)d_in[12];
    const float* b2_iu  = (const float*)d_in[13];
    const int* src_ui = (const int*)d_in[14];
    const int* dst_ui = (const int*)d_in[15];
    const int* src_iu = (const int*)d_in[16];
    const int* dst_iu = (const int*)d_in[17];
    const int E = in_sizes[14];

    const int MU = 100000, MI = 50000;
    const int MUP = 100096, MIP = 50048;  // padded to 128-row multiples

    char* ws = (char*)d_ws;
    // Region AB (phase1: xu_bf, xi_bf, agg1_user, agg1_item | phase2: agg2_user, agg2_item)
    u16* xu_bf     = (u16*)(ws + 0);                    // 25,624,576 B
    u16* xi_bf     = (u16*)(ws + 25624576);             // 12,812,288 B
    u16* agg1_user = (u16*)(ws + 38436864);             // 25,624,576 B
    u16* agg1_item = (u16*)(ws + 64061440);             // 12,812,288 B
    u16* agg2_user = (u16*)(ws + 0);                    // 51,249,152 B (aliases phase1)
    u16* agg2_item = (u16*)(ws + 51249152);             // 25,624,576 B (aliases phase1)
    // Region C: h
    size_t C0 = 76873728;
    u16* h_user = (u16*)(ws + C0);                      // 51,249,152 B
    u16* h_item = (u16*)(ws + C0 + 51249152);           // 25,624,576 B
    // Weights (transposed concat, bf16)
    size_t W0 = C0 + 76873728;  // 153,747,456
    u16* Wt1_ui = (u16*)(ws + W0);
    u16* Wt1_iu = (u16*)(ws + W0 + 131072);
    u16* Wt2_ui = (u16*)(ws + W0 + 262144);
    u16* Wt2_iu = (u16*)(ws + W0 + 524288);
    // Index scratch
    size_t I0 = W0 + 786432;  // 154,533,888
    int* cnt_item = (int*)(ws + I0);
    int* cnt_user = (int*)(ws + I0 + 200000);
    int* off_item = (int*)(ws + I0 + 600000);
    int* off_user = (int*)(ws + I0 + 800000);
    int* cur_item = (int*)(ws + I0 + 1200000);
    int* cur_user = (int*)(ws + I0 + 1400000);
    int* part_a   = (int*)(ws + I0 + 1800000);
    int* part_b   = (int*)(ws + I0 + 1800256);
    int* csr_ui   = (int*)(ws + I0 + 1800512);
    int* csr_iu   = (int*)(ws + I0 + 1800512 + 2400000);

    // zero degree counters (cnt_item | cnt_user are adjacent: 150000 ints)
    zero_k<<<dim3((150000 + 255) / 256), dim3(256), 0, stream>>>(cnt_item, 150000);

    // casts + weight prep
    cast_bf16_k<<<dim3((MU * 128 / 4 + 255) / 256), dim3(256), 0, stream>>>(x_user, xu_bf, MU * 128 / 4);
    cast_bf16_k<<<dim3((MI * 128 / 4 + 255) / 256), dim3(256), 0, stream>>>(x_item, xi_bf, MI * 128 / 4);
    prep_w_k<<<dim3(256), dim3(256), 0, stream>>>(W1l_ui, W1r_ui, Wt1_ui, 128, 256);
    prep_w_k<<<dim3(256), dim3(256), 0, stream>>>(W1l_iu, W1r_iu, Wt1_iu, 128, 256);
    prep_w_k<<<dim3(512), dim3(256), 0, stream>>>(W2l_ui, W2r_ui, Wt2_ui, 256, 512);
    prep_w_k<<<dim3(512), dim3(256), 0, stream>>>(W2l_iu, W2r_iu, Wt2_iu, 256, 512);

    // degree + CSR build
    int gE = (E + 255) / 256;
    count_deg_k<<<dim3(gE), dim3(256), 0, stream>>>(dst_ui, dst_iu, cnt_item, cnt_user, E);
    scan_blk_k<<<dim3(25), dim3(256), 0, stream>>>(cnt_item, off_item, part_a, MI);
    scan_part_k<<<dim3(1), dim3(64), 0, stream>>>(part_a, 25);
    scan_add_k<<<dim3((MI + 255) / 256), dim3(256), 0, stream>>>(off_item, cur_item, part_a, MI);
    scan_blk_k<<<dim3(49), dim3(256), 0, stream>>>(cnt_user, off_user, part_b, MU);
    scan_part_k<<<dim3(1), dim3(64), 0, stream>>>(part_b, 49);
    scan_add_k<<<dim3((MU + 255) / 256), dim3(256), 0, stream>>>(off_user, cur_user, part_b, MU);
    fill_csr_k<<<dim3(gE), dim3(256), 0, stream>>>(src_ui, dst_ui, cur_item, csr_ui, E);
    fill_csr_k<<<dim3(gE), dim3(256), 0, stream>>>(src_iu, dst_iu, cur_user, csr_iu, E);

    // layer 1: aggregate (D=128) then fused concat-GEMM + relu -> h (bf16)
    agg_mean_k<128><<<dim3((MI + 3) / 4), dim3(256), 0, stream>>>(xu_bf, csr_ui, off_item, cnt_item, agg1_item, MI);
    agg_mean_k<128><<<dim3((MU + 3) / 4), dim3(256), 0, stream>>>(xi_bf, csr_iu, off_user, cnt_user, agg1_user, MU);
    gemm_cat_k<256, true, true><<<dim3((MIP / 128) * 2), dim3(256), 0, stream>>>(agg1_item, xi_bf, Wt1_ui, b1_ui, h_item, MI);
    gemm_cat_k<256, true, true><<<dim3((MUP / 128) * 2), dim3(256), 0, stream>>>(agg1_user, xu_bf, Wt1_iu, b1_iu, h_user, MU);

    // layer 2: aggregate (D=256) then concat-GEMM -> d_out (fp32)
    agg_mean_k<256><<<dim3((MI + 3) / 4), dim3(256), 0, stream>>>(h_user, csr_ui, off_item, cnt_item, agg2_item, MI);
    agg_mean_k<256><<<dim3((MU + 3) / 4), dim3(256), 0, stream>>>(h_item, csr_iu, off_user, cnt_user, agg2_user, MU);
    float* out = (float*)d_out;
    gemm_cat_k<512, false, false><<<dim3((MUP / 128) * 2), dim3(256), 0, stream>>>(agg2_user, h_user, Wt2_iu, b2_iu, out, MU);
    gemm_cat_k<512, false, false><<<dim3((MIP / 128) * 2), dim3(256), 0, stream>>>(agg2_item, h_item, Wt2_ui, b2_iu, out + (size_t)MU * 256, MI);
}